// Round 1
// baseline (817.357 us; speedup 1.0000x reference)
//
#include <hip/hip_runtime.h>

typedef unsigned short u16;
typedef unsigned int u32;
typedef __attribute__((ext_vector_type(8))) short bfrag;   // 8 x bf16 (4 VGPRs)
typedef __attribute__((ext_vector_type(4))) float ffrag;   // 4 x f32

constexpr int B_ = 16, CIN = 64, COUT = 64, G = 8, CPG = 8;
constexpr int H = 130, W = 130, HO = 128, WO = 128;
constexpr int OFFC = 144;               // G*2*3*3
constexpr int PLANE_IN = H * W;         // 16900
constexpr int PLANE_OUT = HO * WO;      // 16384

// ws layout:
//   u16   wdB[64*576] @0       : wdB[co*576 + t*64 + ci] = bf16(wd[co][ci][t])  (B-frag layout, deform MFMA)
//   u16   wB1[64*576] @147456B : wB1[co*576 + t*64 + ci] = bf16(w1[co][ci][t])
//   u16   wB2[144*64] @221184B : wB2[oc*64 + ci]         = bf16(w2[oc][ci])
constexpr size_t WB1_BYTE = 36864 * 4;
constexpr size_t WB2_BYTE = WB1_BYTE + 36864 * 2;

__device__ __forceinline__ u16 f2bf(float f) {
    union { u32 u; float f; } t; t.f = f;
    return (u16)((t.u + 0x7FFFu + ((t.u >> 16) & 1u)) >> 16);  // RNE
}

// K0: weight prep (transpose + bf16 conversion).
__global__ void prep_weights(const float* __restrict__ w1,
                             const float* __restrict__ wd,
                             const float* __restrict__ w2,
                             float* __restrict__ wsf) {
    u16* wdB = (u16*)wsf;
    u16* wB1 = (u16*)((char*)wsf + WB1_BYTE);
    u16* wB2 = (u16*)((char*)wsf + WB2_BYTE);
    int idx = blockIdx.x * 256 + threadIdx.x;
    if (idx < 36864) {                        // wdB[co*576 + t*64 + ci]
        int co = idx / 576, r = idx % 576;
        int t = r >> 6, ci = r & 63;
        wdB[idx] = f2bf(wd[(co * 64 + ci) * 9 + t]);
    } else if (idx < 73728) {                 // wB1[co*576 + t*64 + ci]
        int j = idx - 36864;
        int co = j / 576, r = j % 576;
        int t = r >> 6, ci = r & 63;
        wB1[j] = f2bf(w1[(co * 64 + ci) * 9 + t]);
    } else if (idx < 82944) {                 // wB2[oc*64+ci]
        int j = idx - 73728;
        wB2[j] = f2bf(w2[j]);
    }
}

union ConvSmem {
    u16 xs[324 * 72];       // 46656 B : halo tile, xs[p*72 + ci] (row pad 72 -> 2-way banks)
    u16 hs[4][64][72];      // per-wave h buffer [pix][ci], pad 72
};

// K1: fused conv1 (3x3 VALID, 64->64) + conv2 (1x1, 64->144) via bf16 MFMA.
// Block = 16x16 pixel tile, 4 waves; wave w owns rows w*4..w*4+3.
// GEMM1: M=16 pixels/tile (m-tile = spatial row), N=64, K=576 (k = tap*64 + ci).
__global__ __launch_bounds__(256) void conv12(const float* __restrict__ x,
                                              const float* __restrict__ b1,
                                              const float* __restrict__ b2,
                                              const float* __restrict__ wsf,
                                              float* __restrict__ off_out) {
    __shared__ ConvSmem sm;
    const u16* wB1 = (const u16*)((const char*)wsf + WB1_BYTE);
    const u16* wB2 = (const u16*)((const char*)wsf + WB2_BYTE);
    const int b = blockIdx.z;
    const int y0 = blockIdx.y * 16, x0 = blockIdx.x * 16;
    const int tid = threadIdx.x;
    const int wave = tid >> 6, lane = tid & 63;
    const int n16 = lane & 15, quad = lane >> 4;
    const float* xb = x + (size_t)b * CIN * PLANE_IN;

    // stage x tile (18x18 halo x 64 ci) -> LDS bf16, layout [p][ci]
    for (int idx = tid; idx < 324 * 64; idx += 256) {
        int ci = idx / 324, p = idx % 324;            // global-coalesced in p
        float v = xb[(size_t)ci * PLANE_IN + (y0 + p / 18) * W + (x0 + p % 18)];
        sm.xs[p * 72 + ci] = f2bf(v);
    }
    __syncthreads();

    // conv1: acc[mt][nt]; D lane mapping: m=quad*4+reg, n=lane&15
    ffrag acc[4][4];
    #pragma unroll
    for (int nt = 0; nt < 4; ++nt) {
        float bv = b1[nt * 16 + n16];
        #pragma unroll
        for (int mt = 0; mt < 4; ++mt) acc[mt][nt] = ffrag{bv, bv, bv, bv};
    }

    #pragma unroll
    for (int s = 0; s < 18; ++s) {                    // K=576 in 18 slices of 32
        const int tap = s >> 1, cib = (s & 1) * 32;
        const int ti = tap / 3, tj = tap % 3;
        bfrag a[4], bb[4];
        #pragma unroll
        for (int mt = 0; mt < 4; ++mt) {              // A[m=lane&15][k=quad*8+j]
            int p = (wave * 4 + mt + ti) * 18 + n16 + tj;
            a[mt] = *(const bfrag*)&sm.xs[p * 72 + cib + quad * 8];
        }
        #pragma unroll
        for (int nt = 0; nt < 4; ++nt)                // B[n=lane&15][k=quad*8+j]
            bb[nt] = *(const bfrag*)&wB1[(nt * 16 + n16) * 576 + tap * 64 + cib + quad * 8];
        #pragma unroll
        for (int mt = 0; mt < 4; ++mt)
            #pragma unroll
            for (int nt = 0; nt < 4; ++nt)
                acc[mt][nt] = __builtin_amdgcn_mfma_f32_16x16x32_bf16(
                    a[mt], bb[nt], acc[mt][nt], 0, 0, 0);
    }

    __syncthreads();   // all waves done reading xs; reuse as hs

    // D-layout h -> LDS bf16 [pix][ci]; pix = mt*16 + (quad*4+reg), ci = nt*16+n16
    #pragma unroll
    for (int mt = 0; mt < 4; ++mt)
        #pragma unroll
        for (int nt = 0; nt < 4; ++nt)
            #pragma unroll
            for (int r = 0; r < 4; ++r)
                sm.hs[wave][mt * 16 + quad * 4 + r][nt * 16 + n16] = f2bf(acc[mt][nt][r]);
    __syncthreads();   // cheap & definitely safe (cross-lane LDS RAW)

    // conv2 A-frags: A2[m=lane&15][k=quad*8+j], k=ci
    bfrag a2[4][2];
    #pragma unroll
    for (int mt = 0; mt < 4; ++mt)
        #pragma unroll
        for (int s2 = 0; s2 < 2; ++s2)
            a2[mt][s2] = *(const bfrag*)&sm.hs[wave][mt * 16 + n16][s2 * 32 + quad * 8];

    float* offb = off_out + (size_t)b * OFFC * PLANE_OUT;
    #pragma unroll 1
    for (int nt2 = 0; nt2 < 9; ++nt2) {               // N2=144 in 9 n-tiles
        bfrag b2f[2];
        #pragma unroll
        for (int s2 = 0; s2 < 2; ++s2)
            b2f[s2] = *(const bfrag*)&wB2[(nt2 * 16 + n16) * 64 + s2 * 32 + quad * 8];
        float bv = b2[nt2 * 16 + n16];
        #pragma unroll
        for (int mt = 0; mt < 4; ++mt) {
            ffrag acc2 = ffrag{bv, bv, bv, bv};
            acc2 = __builtin_amdgcn_mfma_f32_16x16x32_bf16(a2[mt][0], b2f[0], acc2, 0, 0, 0);
            acc2 = __builtin_amdgcn_mfma_f32_16x16x32_bf16(a2[mt][1], b2f[1], acc2, 0, 0, 0);
            // oc = nt2*16+n16; row = y0+wave*4+mt; cols x0+quad*4 .. +3 -> float4 store
            float* dst = offb + (size_t)(nt2 * 16 + n16) * PLANE_OUT
                       + (y0 + wave * 4 + mt) * WO + x0 + quad * 4;
            *(ffrag*)dst = acc2;
        }
    }
}

// K2: deformable conv via bf16 MFMA.
// Block = 16x16 pixel tile, 4 waves. GEMM: M=256 pixels (16 m-tiles, m-tile = spatial
// row), N=64 (COUT), K=576 split per-tap: per tap t, each thread computes its pixel's
// 64 bilinear-sampled channel values -> bf16 -> LDS A-chunk [256][64] (pad 72), then
// waves consume it as 2 K-slices of 32. acc accumulates across the 9 taps.
// Grid: 1024 1D blocks with bijective XCD swizzle (xcd = wg&7 gets 128 consecutive
// work items = 2 whole batches -> per-XCD x working set ~1 batch (4.3MB ~ L2)).
__global__ __launch_bounds__(256) void deform_k(const float* __restrict__ x,
                                                const float* __restrict__ wsf,
                                                const float* __restrict__ off_in,
                                                float* __restrict__ y_out) {
    __shared__ u16 as[256 * 72];                      // 36864 B
    const u16* wdB = (const u16*)wsf;

    const int wg = blockIdx.x;
    const int swz = (wg & 7) * 128 + (wg >> 3);       // XCD-contiguous, bijective (1024%8==0)
    const int b = swz >> 6;
    const int sp = swz & 63;
    const int y0 = (sp >> 3) * 16, x0 = (sp & 7) * 16;

    const int tid = threadIdx.x;
    const int wave = tid >> 6, lane = tid & 63;
    const int n16 = lane & 15, quad = lane >> 4;
    const int r = tid >> 4, c = tid & 15;
    const int ho = y0 + r, wo = x0 + c;
    const float* xb = x + (size_t)b * CIN * PLANE_IN;
    const float* offb = off_in + (size_t)b * OFFC * PLANE_OUT + ho * WO + wo;

    ffrag acc[4][4];
    #pragma unroll
    for (int mt = 0; mt < 4; ++mt)
        #pragma unroll
        for (int nt = 0; nt < 4; ++nt) acc[mt][nt] = ffrag{0.f, 0.f, 0.f, 0.f};

    #pragma unroll 1
    for (int t = 0; t < 9; ++t) {
        const int ki = t / 3, kj = t % 3;

        // ---- fill phase: thread owns pixel tid; writes A row [tid][0..63] ----
        #pragma unroll 1
        for (int g = 0; g < 8; ++g) {
            float dy = offb[(size_t)((g * 9 + t) * 2 + 0) * PLANE_OUT];
            float dx = offb[(size_t)((g * 9 + t) * 2 + 1) * PLANE_OUT];
            float py = dy + (float)(ho + ki);
            float px = dx + (float)(wo + kj);
            float y0f = floorf(py), x0f = floorf(px);
            float ly = py - y0f, lx = px - x0f;
            int yi0 = (int)y0f, xi0 = (int)x0f;
            int yi1 = yi0 + 1, xi1 = xi0 + 1;
            float vy0 = (yi0 >= 0 && yi0 < H) ? 1.f : 0.f;
            float vy1 = (yi1 >= 0 && yi1 < H) ? 1.f : 0.f;
            float vx0 = (xi0 >= 0 && xi0 < W) ? 1.f : 0.f;
            float vx1 = (xi1 >= 0 && xi1 < W) ? 1.f : 0.f;
            float w00 = (1.f - ly) * (1.f - lx) * vy0 * vx0;
            float w01 = (1.f - ly) * lx         * vy0 * vx1;
            float w10 = ly * (1.f - lx)         * vy1 * vx0;
            float w11 = ly * lx                 * vy1 * vx1;
            int yc0 = min(max(yi0, 0), H - 1), yc1 = min(max(yi1, 0), H - 1);
            int xc0 = min(max(xi0, 0), W - 1), xc1 = min(max(xi1, 0), W - 1);
            int i00 = yc0 * W + xc0, i01 = yc0 * W + xc1;
            int i10 = yc1 * W + xc0, i11 = yc1 * W + xc1;
            const float* xg = xb + (size_t)g * CPG * PLANE_IN;
            union { u16 h[8]; uint4 q; } pk;
            #pragma unroll
            for (int cc = 0; cc < 8; ++cc) {
                const float* xp = xg + cc * PLANE_IN;
                float v = w00 * xp[i00] + w01 * xp[i01]
                        + w10 * xp[i10] + w11 * xp[i11];
                pk.h[cc] = f2bf(v);
            }
            *(uint4*)&as[tid * 72 + g * 8] = pk.q;    // 16B aligned (144*tid + 16*g)
        }
        __syncthreads();

        // ---- MFMA phase: A[m=lane&15][k=quad*8+j], same pattern as conv12 ----
        bfrag a0[4], a1[4];
        #pragma unroll
        for (int mt = 0; mt < 4; ++mt) {
            const u16* ap = &as[((wave * 4 + mt) * 16 + n16) * 72 + quad * 8];
            a0[mt] = *(const bfrag*)ap;
            a1[mt] = *(const bfrag*)(ap + 32);
        }
        #pragma unroll
        for (int nt = 0; nt < 4; ++nt) {
            const u16* wp = &wdB[(size_t)(nt * 16 + n16) * 576 + t * 64 + quad * 8];
            bfrag b0 = *(const bfrag*)wp;
            bfrag b1 = *(const bfrag*)(wp + 32);
            #pragma unroll
            for (int mt = 0; mt < 4; ++mt) {
                acc[mt][nt] = __builtin_amdgcn_mfma_f32_16x16x32_bf16(a0[mt], b0, acc[mt][nt], 0, 0, 0);
                acc[mt][nt] = __builtin_amdgcn_mfma_f32_16x16x32_bf16(a1[mt], b1, acc[mt][nt], 0, 0, 0);
            }
        }
        __syncthreads();   // before next tap overwrites as
    }

    // epilogue: D mapping m=quad*4+reg, n=lane&15 -> row y0+wave*4+mt, cols x0+quad*4..+3
    float* yb = y_out + (size_t)b * COUT * PLANE_OUT;
    #pragma unroll
    for (int nt = 0; nt < 4; ++nt)
        #pragma unroll
        for (int mt = 0; mt < 4; ++mt) {
            float* dst = yb + (size_t)(nt * 16 + n16) * PLANE_OUT
                       + (y0 + wave * 4 + mt) * WO + x0 + quad * 4;
            *(ffrag*)dst = acc[mt][nt];
        }
}

extern "C" void kernel_launch(void* const* d_in, const int* in_sizes, int n_in,
                              void* d_out, int out_size, void* d_ws, size_t ws_size,
                              hipStream_t stream) {
    const float* x  = (const float*)d_in[0];
    const float* w1 = (const float*)d_in[1];
    const float* b1 = (const float*)d_in[2];
    const float* w2 = (const float*)d_in[3];
    const float* b2 = (const float*)d_in[4];
    const float* wd = (const float*)d_in[5];
    float* y_out = (float*)d_out;
    float* off_out = y_out + (size_t)B_ * COUT * PLANE_OUT;   // (y, off) concat
    float* wsf = (float*)d_ws;

    prep_weights<<<324, 256, 0, stream>>>(w1, wd, w2, wsf);
    conv12<<<dim3(8, 8, B_), 256, 0, stream>>>(x, b1, b2, wsf, off_out);
    deform_k<<<1024, 256, 0, stream>>>(x, wsf, off_out, y_out);
}

// Round 2
// 537.909 us; speedup vs baseline: 1.5195x; 1.5195x over previous
//
#include <hip/hip_runtime.h>

typedef unsigned short u16;
typedef unsigned int u32;
typedef __attribute__((ext_vector_type(8))) short bfrag;   // 8 x bf16 (4 VGPRs)
typedef __attribute__((ext_vector_type(4))) float ffrag;   // 4 x f32

constexpr int B_ = 16, CIN = 64, COUT = 64, G = 8, CPG = 8;
constexpr int H = 130, W = 130, HO = 128, WO = 128;
constexpr int OFFC = 144;               // G*2*3*3
constexpr int PLANE_IN = H * W;         // 16900
constexpr int PLANE_OUT = HO * WO;      // 16384

// ws layout:
//   u16   wdB[64*576] @0       : wdB[co*576 + t*64 + ci] = bf16(wd[co][ci][t])
//   u16   wB1[64*576] @147456B : wB1[co*576 + t*64 + ci] = bf16(w1[co][ci][t])
//   u16   wB2[144*64] @221184B : wB2[oc*64 + ci]         = bf16(w2[oc][ci])
//   u16   xt[16*16900*64] @262144B : NHWC bf16 x (if ws_size permits)
constexpr size_t WB1_BYTE = 36864 * 4;
constexpr size_t WB2_BYTE = WB1_BYTE + 36864 * 2;
constexpr size_t XT_BYTE  = 262144;
constexpr size_t XT_SIZE  = (size_t)B_ * PLANE_IN * 64 * 2;   // 34.6 MB

__device__ __forceinline__ u16 f2bf(float f) {
    union { u32 u; float f; } t; t.f = f;
    return (u16)((t.u + 0x7FFFu + ((t.u >> 16) & 1u)) >> 16);  // RNE
}
__device__ __forceinline__ float bf2f(short h) {
    union { u32 u; float f; } t; t.u = ((u32)(u16)h) << 16;
    return t.f;
}

// K0: weight prep (transpose + bf16 conversion).
__global__ void prep_weights(const float* __restrict__ w1,
                             const float* __restrict__ wd,
                             const float* __restrict__ w2,
                             float* __restrict__ wsf) {
    u16* wdB = (u16*)wsf;
    u16* wB1 = (u16*)((char*)wsf + WB1_BYTE);
    u16* wB2 = (u16*)((char*)wsf + WB2_BYTE);
    int idx = blockIdx.x * 256 + threadIdx.x;
    if (idx < 36864) {                        // wdB[co*576 + t*64 + ci]
        int co = idx / 576, r = idx % 576;
        int t = r >> 6, ci = r & 63;
        wdB[idx] = f2bf(wd[(co * 64 + ci) * 9 + t]);
    } else if (idx < 73728) {                 // wB1[co*576 + t*64 + ci]
        int j = idx - 36864;
        int co = j / 576, r = j % 576;
        int t = r >> 6, ci = r & 63;
        wB1[j] = f2bf(w1[(co * 64 + ci) * 9 + t]);
    } else if (idx < 82944) {                 // wB2[oc*64+ci]
        int j = idx - 73728;
        wB2[j] = f2bf(w2[j]);
    }
}

// K0b: x NCHW f32 -> NHWC bf16. Thread owns one pixel; reads coalesced along
// spatial (lanes = consecutive pixels), writes 8x16B covering its 128B chunk
// (L2 merges neighboring lanes' chunks into full lines).
__global__ __launch_bounds__(256) void x_to_nhwc(const float* __restrict__ x,
                                                 u16* __restrict__ xt) {
    int p = blockIdx.x * 256 + threadIdx.x;          // global pixel
    if (p >= B_ * PLANE_IN) return;
    int b = p / PLANE_IN, pp = p % PLANE_IN;
    const float* xb = x + (size_t)b * CIN * PLANE_IN + pp;
    u16* dst = xt + (size_t)p * 64;
    #pragma unroll
    for (int oct = 0; oct < 8; ++oct) {
        union { u16 h[8]; uint4 q; } pk;
        #pragma unroll
        for (int j = 0; j < 8; ++j)
            pk.h[j] = f2bf(xb[(size_t)(oct * 8 + j) * PLANE_IN]);
        *(uint4*)(dst + oct * 8) = pk.q;
    }
}

union ConvSmem {
    u16 xs[324 * 72];       // 46656 B : halo tile, xs[p*72 + ci]
    u16 hs[4][64][72];      // per-wave h buffer [pix][ci]
};

// K1: fused conv1 (3x3 VALID, 64->64) + conv2 (1x1, 64->144) via bf16 MFMA.
template<bool XT>
__global__ __launch_bounds__(256) void conv12(const float* __restrict__ x,
                                              const u16* __restrict__ xt,
                                              const float* __restrict__ b1,
                                              const float* __restrict__ b2,
                                              const float* __restrict__ wsf,
                                              float* __restrict__ off_out) {
    __shared__ ConvSmem sm;
    const u16* wB1 = (const u16*)((const char*)wsf + WB1_BYTE);
    const u16* wB2 = (const u16*)((const char*)wsf + WB2_BYTE);
    const int b = blockIdx.z;
    const int y0 = blockIdx.y * 16, x0 = blockIdx.x * 16;
    const int tid = threadIdx.x;
    const int wave = tid >> 6, lane = tid & 63;
    const int n16 = lane & 15, quad = lane >> 4;

    // stage x tile (18x18 halo x 64 ci) -> LDS bf16, layout [p][ci]
    if constexpr (XT) {
        const u16* xtb = xt + (size_t)b * PLANE_IN * 64;
        for (int idx = tid; idx < 324 * 8; idx += 256) {
            int p = idx >> 3, oct = idx & 7;
            *(bfrag*)&sm.xs[p * 72 + oct * 8] =
                *(const bfrag*)&xtb[((size_t)(y0 + p / 18) * W + x0 + p % 18) * 64 + oct * 8];
        }
    } else {
        const float* xb = x + (size_t)b * CIN * PLANE_IN;
        for (int idx = tid; idx < 324 * 64; idx += 256) {
            int ci = idx / 324, p = idx % 324;
            float v = xb[(size_t)ci * PLANE_IN + (y0 + p / 18) * W + (x0 + p % 18)];
            sm.xs[p * 72 + ci] = f2bf(v);
        }
    }
    __syncthreads();

    ffrag acc[4][4];
    #pragma unroll
    for (int nt = 0; nt < 4; ++nt) {
        float bv = b1[nt * 16 + n16];
        #pragma unroll
        for (int mt = 0; mt < 4; ++mt) acc[mt][nt] = ffrag{bv, bv, bv, bv};
    }

    #pragma unroll
    for (int s = 0; s < 18; ++s) {                    // K=576 in 18 slices of 32
        const int tap = s >> 1, cib = (s & 1) * 32;
        const int ti = tap / 3, tj = tap % 3;
        bfrag a[4], bb[4];
        #pragma unroll
        for (int mt = 0; mt < 4; ++mt) {              // A[m=lane&15][k=quad*8+j]
            int p = (wave * 4 + mt + ti) * 18 + n16 + tj;
            a[mt] = *(const bfrag*)&sm.xs[p * 72 + cib + quad * 8];
        }
        #pragma unroll
        for (int nt = 0; nt < 4; ++nt)                // B[n=lane&15][k=quad*8+j]
            bb[nt] = *(const bfrag*)&wB1[(nt * 16 + n16) * 576 + tap * 64 + cib + quad * 8];
        #pragma unroll
        for (int mt = 0; mt < 4; ++mt)
            #pragma unroll
            for (int nt = 0; nt < 4; ++nt)
                acc[mt][nt] = __builtin_amdgcn_mfma_f32_16x16x32_bf16(
                    a[mt], bb[nt], acc[mt][nt], 0, 0, 0);
    }

    __syncthreads();

    #pragma unroll
    for (int mt = 0; mt < 4; ++mt)
        #pragma unroll
        for (int nt = 0; nt < 4; ++nt)
            #pragma unroll
            for (int r = 0; r < 4; ++r)
                sm.hs[wave][mt * 16 + quad * 4 + r][nt * 16 + n16] = f2bf(acc[mt][nt][r]);
    __syncthreads();

    bfrag a2[4][2];
    #pragma unroll
    for (int mt = 0; mt < 4; ++mt)
        #pragma unroll
        for (int s2 = 0; s2 < 2; ++s2)
            a2[mt][s2] = *(const bfrag*)&sm.hs[wave][mt * 16 + n16][s2 * 32 + quad * 8];

    float* offb = off_out + (size_t)b * OFFC * PLANE_OUT;
    #pragma unroll 1
    for (int nt2 = 0; nt2 < 9; ++nt2) {               // N2=144 in 9 n-tiles
        bfrag b2f[2];
        #pragma unroll
        for (int s2 = 0; s2 < 2; ++s2)
            b2f[s2] = *(const bfrag*)&wB2[(nt2 * 16 + n16) * 64 + s2 * 32 + quad * 8];
        float bv = b2[nt2 * 16 + n16];
        #pragma unroll
        for (int mt = 0; mt < 4; ++mt) {
            ffrag acc2 = ffrag{bv, bv, bv, bv};
            acc2 = __builtin_amdgcn_mfma_f32_16x16x32_bf16(a2[mt][0], b2f[0], acc2, 0, 0, 0);
            acc2 = __builtin_amdgcn_mfma_f32_16x16x32_bf16(a2[mt][1], b2f[1], acc2, 0, 0, 0);
            float* dst = offb + (size_t)(nt2 * 16 + n16) * PLANE_OUT
                       + (y0 + wave * 4 + mt) * WO + x0 + quad * 4;
            *(ffrag*)dst = acc2;
        }
    }
}

// K2: deformable conv via bf16 MFMA with direct per-lane A-fragment fill.
// Block = 512 threads (8 waves), tile 16x16 px. Wave w owns pixel rows w*2, w*2+1
// (two 16x16x32 m-tiles). In the A-fragment, lane (n16,quad) holds
// A[m=n16][k=quad*8+j]; k=ci maps quad->offset-group. So lane (n16,quad)
// bilinear-samples pixel (row, col=n16) for g=quad (a0) and g=quad+4 (a1):
// every lane computes exactly its own fragment in registers.
// NO LDS, NO BARRIERS -> waves independent, gather latency hidden by occupancy.
template<bool XT>
__global__ __launch_bounds__(512, 4) void deform_k(const float* __restrict__ x,
                                                   const u16* __restrict__ xt,
                                                   const float* __restrict__ wsf,
                                                   const float* __restrict__ off_in,
                                                   float* __restrict__ y_out) {
    const u16* wdB = (const u16*)wsf;

    const int wg = blockIdx.x;
    const int swz = (wg & 7) * 128 + (wg >> 3);       // XCD-contiguous, bijective
    const int b = swz >> 6, sp = swz & 63;
    const int y0 = (sp >> 3) * 16, x0 = (sp & 7) * 16;

    const int tid = threadIdx.x;
    const int wave = tid >> 6, lane = tid & 63;
    const int n16 = lane & 15, quad = lane >> 4;
    const int wo = x0 + n16;

    const float* offbase = off_in + (size_t)b * OFFC * PLANE_OUT + x0 + n16;
    const u16* xtb = xt + (size_t)b * PLANE_IN * 64;
    const float* xb = x + (size_t)b * CIN * PLANE_IN;

    ffrag acc[2][4];
    #pragma unroll
    for (int mt = 0; mt < 2; ++mt)
        #pragma unroll
        for (int nt = 0; nt < 4; ++nt) acc[mt][nt] = ffrag{0.f, 0.f, 0.f, 0.f};

    #pragma unroll 1
    for (int t = 0; t < 9; ++t) {
        const int ki = t / 3, kj = t % 3;
        bfrag a0[2], a1[2];

        #pragma unroll
        for (int mt = 0; mt < 2; ++mt) {
            const int ho = y0 + wave * 2 + mt;
            #pragma unroll
            for (int half = 0; half < 2; ++half) {
                const int g = quad + half * 4;
                const float* ob = offbase + ho * WO + (size_t)((g * 9 + t) * 2) * PLANE_OUT;
                float dy = ob[0];
                float dx = ob[PLANE_OUT];
                float py = dy + (float)(ho + ki);
                float px = dx + (float)(wo + kj);
                float y0f = floorf(py), x0f = floorf(px);
                float ly = py - y0f, lx = px - x0f;
                int yi0 = (int)y0f, xi0 = (int)x0f;
                int yi1 = yi0 + 1, xi1 = xi0 + 1;
                float vy0 = (yi0 >= 0 && yi0 < H) ? 1.f : 0.f;
                float vy1 = (yi1 >= 0 && yi1 < H) ? 1.f : 0.f;
                float vx0 = (xi0 >= 0 && xi0 < W) ? 1.f : 0.f;
                float vx1 = (xi1 >= 0 && xi1 < W) ? 1.f : 0.f;
                float w00 = (1.f - ly) * (1.f - lx) * vy0 * vx0;
                float w01 = (1.f - ly) * lx         * vy0 * vx1;
                float w10 = ly * (1.f - lx)         * vy1 * vx0;
                float w11 = ly * lx                 * vy1 * vx1;
                int yc0 = min(max(yi0, 0), H - 1), yc1 = min(max(yi1, 0), H - 1);
                int xc0 = min(max(xi0, 0), W - 1), xc1 = min(max(xi1, 0), W - 1);
                union { u16 h[8]; bfrag f; } pk;
                if constexpr (XT) {
                    bfrag q00 = *(const bfrag*)&xtb[((size_t)(yc0 * W + xc0)) * 64 + g * 8];
                    bfrag q01 = *(const bfrag*)&xtb[((size_t)(yc0 * W + xc1)) * 64 + g * 8];
                    bfrag q10 = *(const bfrag*)&xtb[((size_t)(yc1 * W + xc0)) * 64 + g * 8];
                    bfrag q11 = *(const bfrag*)&xtb[((size_t)(yc1 * W + xc1)) * 64 + g * 8];
                    #pragma unroll
                    for (int j = 0; j < 8; ++j) {
                        float v = w00 * bf2f(q00[j]) + w01 * bf2f(q01[j])
                                + w10 * bf2f(q10[j]) + w11 * bf2f(q11[j]);
                        pk.h[j] = f2bf(v);
                    }
                } else {
                    int i00 = yc0 * W + xc0, i01 = yc0 * W + xc1;
                    int i10 = yc1 * W + xc0, i11 = yc1 * W + xc1;
                    const float* xg = xb + (size_t)g * CPG * PLANE_IN;
                    #pragma unroll
                    for (int cc = 0; cc < 8; ++cc) {
                        const float* xp = xg + cc * PLANE_IN;
                        float v = w00 * xp[i00] + w01 * xp[i01]
                                + w10 * xp[i10] + w11 * xp[i11];
                        pk.h[cc] = f2bf(v);
                    }
                }
                if (half == 0) a0[mt] = pk.f; else a1[mt] = pk.f;
            }
        }

        // MFMA: A per-lane in regs; B from L2-resident wdB (same pattern as conv12)
        #pragma unroll
        for (int nt = 0; nt < 4; ++nt) {
            const u16* wp = &wdB[(size_t)(nt * 16 + n16) * 576 + t * 64 + quad * 8];
            bfrag b0 = *(const bfrag*)wp;
            bfrag b1 = *(const bfrag*)(wp + 32);
            #pragma unroll
            for (int mt = 0; mt < 2; ++mt) {
                acc[mt][nt] = __builtin_amdgcn_mfma_f32_16x16x32_bf16(a0[mt], b0, acc[mt][nt], 0, 0, 0);
                acc[mt][nt] = __builtin_amdgcn_mfma_f32_16x16x32_bf16(a1[mt], b1, acc[mt][nt], 0, 0, 0);
            }
        }
    }

    // epilogue: D mapping m=quad*4+reg (pixel col), n=n16 (co within n-tile)
    float* yb = y_out + (size_t)b * COUT * PLANE_OUT;
    #pragma unroll
    for (int nt = 0; nt < 4; ++nt)
        #pragma unroll
        for (int mt = 0; mt < 2; ++mt) {
            float* dst = yb + (size_t)(nt * 16 + n16) * PLANE_OUT
                       + (y0 + wave * 2 + mt) * WO + x0 + quad * 4;
            *(ffrag*)dst = acc[mt][nt];
        }
}

extern "C" void kernel_launch(void* const* d_in, const int* in_sizes, int n_in,
                              void* d_out, int out_size, void* d_ws, size_t ws_size,
                              hipStream_t stream) {
    const float* x  = (const float*)d_in[0];
    const float* w1 = (const float*)d_in[1];
    const float* b1 = (const float*)d_in[2];
    const float* w2 = (const float*)d_in[3];
    const float* b2 = (const float*)d_in[4];
    const float* wd = (const float*)d_in[5];
    float* y_out = (float*)d_out;
    float* off_out = y_out + (size_t)B_ * COUT * PLANE_OUT;   // (y, off) concat
    float* wsf = (float*)d_ws;
    u16* xt = (u16*)((char*)d_ws + XT_BYTE);
    const bool use_xt = ws_size >= XT_BYTE + XT_SIZE;

    prep_weights<<<324, 256, 0, stream>>>(w1, wd, w2, wsf);
    if (use_xt) {
        x_to_nhwc<<<(B_ * PLANE_IN + 255) / 256, 256, 0, stream>>>(x, xt);
        conv12<true><<<dim3(8, 8, B_), 256, 0, stream>>>(x, xt, b1, b2, wsf, off_out);
        deform_k<true><<<1024, 512, 0, stream>>>(x, xt, wsf, off_out, y_out);
    } else {
        conv12<false><<<dim3(8, 8, B_), 256, 0, stream>>>(x, xt, b1, b2, wsf, off_out);
        deform_k<false><<<1024, 512, 0, stream>>>(x, xt, wsf, off_out, y_out);
    }
}

// Round 3
// 530.220 us; speedup vs baseline: 1.5415x; 1.0145x over previous
//
#include <hip/hip_runtime.h>

typedef unsigned short u16;
typedef unsigned int u32;
typedef __attribute__((ext_vector_type(8))) short bfrag;   // 8 x bf16 (4 VGPRs)
typedef __attribute__((ext_vector_type(4))) float ffrag;   // 4 x f32

constexpr int B_ = 16, CIN = 64, COUT = 64, G = 8, CPG = 8;
constexpr int H = 130, W = 130, HO = 128, WO = 128;
constexpr int OFFC = 144;               // G*2*3*3
constexpr int PLANE_IN = H * W;         // 16900
constexpr int PLANE_OUT = HO * WO;      // 16384

// ws layout:
//   u16   wdB[64*576] @0       : wdB[co*576 + t*64 + ci] = bf16(wd[co][ci][t])
//   u16   wB1[64*576] @147456B : wB1[co*576 + t*64 + ci] = bf16(w1[co][ci][t])
//   u16   wB2[144*64] @221184B : wB2[oc*64 + ci]         = bf16(w2[oc][ci])
//   u16   xt[16*16900*64] @262144B : NHWC bf16 x (if ws_size permits)
constexpr size_t WB1_BYTE = 36864 * 4;
constexpr size_t WB2_BYTE = WB1_BYTE + 36864 * 2;
constexpr size_t XT_BYTE  = 262144;
constexpr size_t XT_SIZE  = (size_t)B_ * PLANE_IN * 64 * 2;   // 34.6 MB

__device__ __forceinline__ u16 f2bf(float f) {
    union { u32 u; float f; } t; t.f = f;
    return (u16)((t.u + 0x7FFFu + ((t.u >> 16) & 1u)) >> 16);  // RNE
}
__device__ __forceinline__ float bf2f(short h) {
    union { u32 u; float f; } t; t.u = ((u32)(u16)h) << 16;
    return t.f;
}

// K0: weight prep (transpose + bf16 conversion).
__global__ void prep_weights(const float* __restrict__ w1,
                             const float* __restrict__ wd,
                             const float* __restrict__ w2,
                             float* __restrict__ wsf) {
    u16* wdB = (u16*)wsf;
    u16* wB1 = (u16*)((char*)wsf + WB1_BYTE);
    u16* wB2 = (u16*)((char*)wsf + WB2_BYTE);
    int idx = blockIdx.x * 256 + threadIdx.x;
    if (idx < 36864) {                        // wdB[co*576 + t*64 + ci]
        int co = idx / 576, r = idx % 576;
        int t = r >> 6, ci = r & 63;
        wdB[idx] = f2bf(wd[(co * 64 + ci) * 9 + t]);
    } else if (idx < 73728) {                 // wB1[co*576 + t*64 + ci]
        int j = idx - 36864;
        int co = j / 576, r = j % 576;
        int t = r >> 6, ci = r & 63;
        wB1[j] = f2bf(w1[(co * 64 + ci) * 9 + t]);
    } else if (idx < 82944) {                 // wB2[oc*64+ci]
        int j = idx - 73728;
        wB2[j] = f2bf(w2[j]);
    }
}

// K0b: x NCHW f32 -> NHWC bf16.
__global__ __launch_bounds__(256) void x_to_nhwc(const float* __restrict__ x,
                                                 u16* __restrict__ xt) {
    int p = blockIdx.x * 256 + threadIdx.x;          // global pixel
    if (p >= B_ * PLANE_IN) return;
    int b = p / PLANE_IN, pp = p % PLANE_IN;
    const float* xb = x + (size_t)b * CIN * PLANE_IN + pp;
    u16* dst = xt + (size_t)p * 64;
    #pragma unroll
    for (int oct = 0; oct < 8; ++oct) {
        union { u16 h[8]; uint4 q; } pk;
        #pragma unroll
        for (int j = 0; j < 8; ++j)
            pk.h[j] = f2bf(xb[(size_t)(oct * 8 + j) * PLANE_IN]);
        *(uint4*)(dst + oct * 8) = pk.q;
    }
}

// LDS for conv12: linear 128B rows + XOR swizzle byte ^= (p&7)<<4 (T2).
// Any 16B-aligned padded stride keeps dword-stride % 4 == 0 -> >=8-way bank
// conflict on the A-frag ds_read_b128 (all 64 lanes read different rows at the
// same col). XOR spreads 8 consecutive rows across 8 distinct 16B slots.
union ConvSmem {
    char xsb[324 * 128];       // 41472 B : halo tile [p][ci] swizzled
    char hsb[4][64 * 128];     // 32768 B : per-wave h buffer [pix][ci] swizzled
};
__device__ __forceinline__ int swz128(int row, int bytecol) {
    return row * 128 + (bytecol ^ ((row & 7) << 4));
}

// K1: fused conv1 (3x3 VALID, 64->64) + conv2 (1x1, 64->144) via bf16 MFMA.
template<bool XT>
__global__ __launch_bounds__(256) void conv12(const float* __restrict__ x,
                                              const u16* __restrict__ xt,
                                              const float* __restrict__ b1,
                                              const float* __restrict__ b2,
                                              const float* __restrict__ wsf,
                                              float* __restrict__ off_out) {
    __shared__ ConvSmem sm;
    const u16* wB1 = (const u16*)((const char*)wsf + WB1_BYTE);
    const u16* wB2 = (const u16*)((const char*)wsf + WB2_BYTE);
    const int b = blockIdx.z;
    const int y0 = blockIdx.y * 16, x0 = blockIdx.x * 16;
    const int tid = threadIdx.x;
    const int wave = tid >> 6, lane = tid & 63;
    const int n16 = lane & 15, quad = lane >> 4;

    // stage x tile (18x18 halo x 64 ci) -> LDS bf16, layout [p][ci] swizzled
    if constexpr (XT) {
        const u16* xtb = xt + (size_t)b * PLANE_IN * 64;
        for (int idx = tid; idx < 324 * 8; idx += 256) {
            int p = idx >> 3, oct = idx & 7;
            *(bfrag*)(sm.xsb + swz128(p, oct * 16)) =
                *(const bfrag*)&xtb[((size_t)(y0 + p / 18) * W + x0 + p % 18) * 64 + oct * 8];
        }
    } else {
        const float* xb = x + (size_t)b * CIN * PLANE_IN;
        for (int idx = tid; idx < 324 * 64; idx += 256) {
            int ci = idx / 324, p = idx % 324;
            float v = xb[(size_t)ci * PLANE_IN + (y0 + p / 18) * W + (x0 + p % 18)];
            *(u16*)(sm.xsb + swz128(p, ci * 2)) = f2bf(v);
        }
    }
    __syncthreads();

    ffrag acc[4][4];
    #pragma unroll
    for (int nt = 0; nt < 4; ++nt) {
        float bv = b1[nt * 16 + n16];
        #pragma unroll
        for (int mt = 0; mt < 4; ++mt) acc[mt][nt] = ffrag{bv, bv, bv, bv};
    }

    #pragma unroll
    for (int s = 0; s < 18; ++s) {                    // K=576 in 18 slices of 32
        const int tap = s >> 1, cib = (s & 1) * 32;
        const int ti = tap / 3, tj = tap % 3;
        bfrag a[4], bb[4];
        #pragma unroll
        for (int mt = 0; mt < 4; ++mt) {              // A[m=lane&15][k=quad*8+j]
            int p = (wave * 4 + mt + ti) * 18 + n16 + tj;
            a[mt] = *(const bfrag*)(sm.xsb + swz128(p, cib * 2 + quad * 16));
        }
        #pragma unroll
        for (int nt = 0; nt < 4; ++nt)                // B[n=lane&15][k=quad*8+j]
            bb[nt] = *(const bfrag*)&wB1[(nt * 16 + n16) * 576 + tap * 64 + cib + quad * 8];
        #pragma unroll
        for (int mt = 0; mt < 4; ++mt)
            #pragma unroll
            for (int nt = 0; nt < 4; ++nt)
                acc[mt][nt] = __builtin_amdgcn_mfma_f32_16x16x32_bf16(
                    a[mt], bb[nt], acc[mt][nt], 0, 0, 0);
    }

    __syncthreads();

    #pragma unroll
    for (int mt = 0; mt < 4; ++mt)
        #pragma unroll
        for (int nt = 0; nt < 4; ++nt)
            #pragma unroll
            for (int r = 0; r < 4; ++r)
                *(u16*)(sm.hsb[wave] + swz128(mt * 16 + quad * 4 + r, (nt * 16 + n16) * 2))
                    = f2bf(acc[mt][nt][r]);
    __syncthreads();

    bfrag a2[4][2];
    #pragma unroll
    for (int mt = 0; mt < 4; ++mt)
        #pragma unroll
        for (int s2 = 0; s2 < 2; ++s2)
            a2[mt][s2] = *(const bfrag*)(sm.hsb[wave]
                        + swz128(mt * 16 + n16, s2 * 64 + quad * 16));

    float* offb = off_out + (size_t)b * OFFC * PLANE_OUT;
    #pragma unroll 1
    for (int nt2 = 0; nt2 < 9; ++nt2) {               // N2=144 in 9 n-tiles
        bfrag b2f[2];
        #pragma unroll
        for (int s2 = 0; s2 < 2; ++s2)
            b2f[s2] = *(const bfrag*)&wB2[(nt2 * 16 + n16) * 64 + s2 * 32 + quad * 8];
        float bv = b2[nt2 * 16 + n16];
        #pragma unroll
        for (int mt = 0; mt < 4; ++mt) {
            ffrag acc2 = ffrag{bv, bv, bv, bv};
            acc2 = __builtin_amdgcn_mfma_f32_16x16x32_bf16(a2[mt][0], b2f[0], acc2, 0, 0, 0);
            acc2 = __builtin_amdgcn_mfma_f32_16x16x32_bf16(a2[mt][1], b2f[1], acc2, 0, 0, 0);
            float* dst = offb + (size_t)(nt2 * 16 + n16) * PLANE_OUT
                       + (y0 + wave * 4 + mt) * WO + x0 + quad * 4;
            *(ffrag*)dst = acc2;
        }
    }
}

__device__ __forceinline__ bfrag interp4(const bfrag* q, const float* w) {
    union { u16 h[8]; bfrag f; } pk;
    #pragma unroll
    for (int j = 0; j < 8; ++j) {
        float v = w[0] * bf2f(q[0][j]) + w[1] * bf2f(q[1][j])
                + w[2] * bf2f(q[2][j]) + w[3] * bf2f(q[3][j]);
        pk.h[j] = f2bf(v);
    }
    return pk.f;
}

// K2: deformable conv via bf16 MFMA, ILP-pipelined fill.
// Block = 256 threads (4 waves), tile 8 rows x 16 cols; wave owns rows wave*2,+1.
// Lane (n16,quad) holds A[m=n16][k=quad*8+j]; task tk = mt*2+half samples pixel
// (row mt, col n16) for group g = quad + half*4. Per tap: all 8 offsets loaded
// up front, NEXT tap's offsets prefetched immediately (kills the off-stream
// round-trip in the chain), gathers staged 2 tasks deep so loads overlap interp.
template<bool XT>
__global__ __launch_bounds__(256, 2) void deform_k(const float* __restrict__ x,
                                                   const u16* __restrict__ xt,
                                                   const float* __restrict__ wsf,
                                                   const float* __restrict__ off_in,
                                                   float* __restrict__ y_out) {
    const u16* wdB = (const u16*)wsf;

    const int wg = blockIdx.x;
    const int swz = (wg & 7) * 256 + (wg >> 3);       // XCD-contiguous, bijective (2048%8==0)
    const int b = swz >> 7, sp = swz & 127;
    const int y0 = (sp >> 3) * 8, x0 = (sp & 7) * 16;

    const int tid = threadIdx.x;
    const int wave = tid >> 6, lane = tid & 63;
    const int n16 = lane & 15, quad = lane >> 4;
    const int wo = x0 + n16;

    const float* offbase = off_in + (size_t)b * OFFC * PLANE_OUT + x0 + n16;
    const u16* xtb = xt + (size_t)b * PLANE_IN * 64;
    const float* xb = x + (size_t)b * CIN * PLANE_IN;

    ffrag acc[2][4];
    #pragma unroll
    for (int mt = 0; mt < 2; ++mt)
        #pragma unroll
        for (int nt = 0; nt < 4; ++nt) acc[mt][nt] = ffrag{0.f, 0.f, 0.f, 0.f};

    // prefetched offsets for the upcoming tap; tk = mt*2 + half
    float pdy[4], pdx[4];
    #pragma unroll
    for (int tk = 0; tk < 4; ++tk) {
        const int mt = tk >> 1, g = quad + (tk & 1) * 4;
        const float* ob = offbase + (y0 + wave * 2 + mt) * WO
                        + (size_t)(g * 9 * 2) * PLANE_OUT;      // t = 0
        pdy[tk] = ob[0];
        pdx[tk] = ob[PLANE_OUT];
    }

    #pragma unroll 1
    for (int t = 0; t < 9; ++t) {
        const int ki = t / 3, kj = t % 3;

        float dyv[4], dxv[4];
        #pragma unroll
        for (int tk = 0; tk < 4; ++tk) { dyv[tk] = pdy[tk]; dxv[tk] = pdx[tk]; }

        // prefetch next tap's 8 offsets (independent of everything below)
        if (t < 8) {
            #pragma unroll
            for (int tk = 0; tk < 4; ++tk) {
                const int mt = tk >> 1, g = quad + (tk & 1) * 4;
                const float* ob = offbase + (y0 + wave * 2 + mt) * WO
                                + (size_t)((g * 9 + t + 1) * 2) * PLANE_OUT;
                pdy[tk] = ob[0];
                pdx[tk] = ob[PLANE_OUT];
            }
        }

        // addresses + bilinear weights for all 4 tasks
        int idxq[4][4];
        float wq[4][4];
        #pragma unroll
        for (int tk = 0; tk < 4; ++tk) {
            const int mt = tk >> 1, g = quad + (tk & 1) * 4;
            const int ho = y0 + wave * 2 + mt;
            float py = dyv[tk] + (float)(ho + ki);
            float px = dxv[tk] + (float)(wo + kj);
            float y0f = floorf(py), x0f = floorf(px);
            float ly = py - y0f, lx = px - x0f;
            int yi0 = (int)y0f, xi0 = (int)x0f;
            int yi1 = yi0 + 1, xi1 = xi0 + 1;
            float vy0 = (yi0 >= 0 && yi0 < H) ? 1.f : 0.f;
            float vy1 = (yi1 >= 0 && yi1 < H) ? 1.f : 0.f;
            float vx0 = (xi0 >= 0 && xi0 < W) ? 1.f : 0.f;
            float vx1 = (xi1 >= 0 && xi1 < W) ? 1.f : 0.f;
            wq[tk][0] = (1.f - ly) * (1.f - lx) * vy0 * vx0;
            wq[tk][1] = (1.f - ly) * lx         * vy0 * vx1;
            wq[tk][2] = ly * (1.f - lx)         * vy1 * vx0;
            wq[tk][3] = ly * lx                 * vy1 * vx1;
            int yc0 = min(max(yi0, 0), H - 1), yc1 = min(max(yi1, 0), H - 1);
            int xc0 = min(max(xi0, 0), W - 1), xc1 = min(max(xi1, 0), W - 1);
            idxq[tk][0] = (yc0 * W + xc0) * 64 + g * 8;
            idxq[tk][1] = (yc0 * W + xc1) * 64 + g * 8;
            idxq[tk][2] = (yc1 * W + xc0) * 64 + g * 8;
            idxq[tk][3] = (yc1 * W + xc1) * 64 + g * 8;
        }

        bfrag frag[4];
        if constexpr (XT) {
            // pipelined gathers: issue tasks 0,1; weights; interp0; issue 2;
            // interp1; issue 3; interp2; interp3.
            bfrag q0[4], q1[4], q2[4], q3[4];
            #pragma unroll
            for (int c = 0; c < 4; ++c) q0[c] = *(const bfrag*)&xtb[idxq[0][c]];
            #pragma unroll
            for (int c = 0; c < 4; ++c) q1[c] = *(const bfrag*)&xtb[idxq[1][c]];
            bfrag bw0[4], bw1[4];
            #pragma unroll
            for (int nt = 0; nt < 4; ++nt) {
                const u16* wp = &wdB[(size_t)(nt * 16 + n16) * 576 + t * 64 + quad * 8];
                bw0[nt] = *(const bfrag*)wp;
                bw1[nt] = *(const bfrag*)(wp + 32);
            }
            frag[0] = interp4(q0, wq[0]);
            #pragma unroll
            for (int c = 0; c < 4; ++c) q2[c] = *(const bfrag*)&xtb[idxq[2][c]];
            frag[1] = interp4(q1, wq[1]);
            #pragma unroll
            for (int c = 0; c < 4; ++c) q3[c] = *(const bfrag*)&xtb[idxq[3][c]];
            frag[2] = interp4(q2, wq[2]);
            frag[3] = interp4(q3, wq[3]);

            #pragma unroll
            for (int nt = 0; nt < 4; ++nt)
                #pragma unroll
                for (int mt = 0; mt < 2; ++mt) {
                    acc[mt][nt] = __builtin_amdgcn_mfma_f32_16x16x32_bf16(
                        frag[mt * 2 + 0], bw0[nt], acc[mt][nt], 0, 0, 0);
                    acc[mt][nt] = __builtin_amdgcn_mfma_f32_16x16x32_bf16(
                        frag[mt * 2 + 1], bw1[nt], acc[mt][nt], 0, 0, 0);
                }
        } else {
            // fallback: NCHW f32 gathers (slower, correctness path)
            #pragma unroll
            for (int tk = 0; tk < 4; ++tk) {
                const int g = quad + (tk & 1) * 4;
                const float* xg = xb + (size_t)g * CPG * PLANE_IN;
                union { u16 h[8]; bfrag f; } pk;
                #pragma unroll
                for (int cc = 0; cc < 8; ++cc) {
                    const float* xp = xg + cc * PLANE_IN;
                    int sh = (idxq[tk][0] - g * 8) / 64;   // recover linear pixel idx
                    int s01 = (idxq[tk][1] - g * 8) / 64;
                    int s10 = (idxq[tk][2] - g * 8) / 64;
                    int s11 = (idxq[tk][3] - g * 8) / 64;
                    float v = wq[tk][0] * xp[sh] + wq[tk][1] * xp[s01]
                            + wq[tk][2] * xp[s10] + wq[tk][3] * xp[s11];
                    pk.h[cc] = f2bf(v);
                }
                frag[tk] = pk.f;
            }
            #pragma unroll
            for (int nt = 0; nt < 4; ++nt) {
                const u16* wp = &wdB[(size_t)(nt * 16 + n16) * 576 + t * 64 + quad * 8];
                bfrag b0 = *(const bfrag*)wp;
                bfrag b1 = *(const bfrag*)(wp + 32);
                #pragma unroll
                for (int mt = 0; mt < 2; ++mt) {
                    acc[mt][nt] = __builtin_amdgcn_mfma_f32_16x16x32_bf16(
                        frag[mt * 2 + 0], b0, acc[mt][nt], 0, 0, 0);
                    acc[mt][nt] = __builtin_amdgcn_mfma_f32_16x16x32_bf16(
                        frag[mt * 2 + 1], b1, acc[mt][nt], 0, 0, 0);
                }
            }
        }
    }

    // epilogue: lane holds D[m=quad*4+r][n=n16]; m = pixel col, n = co-in-tile
    float* yb = y_out + (size_t)b * COUT * PLANE_OUT;
    #pragma unroll
    for (int nt = 0; nt < 4; ++nt)
        #pragma unroll
        for (int mt = 0; mt < 2; ++mt) {
            float* dst = yb + (size_t)(nt * 16 + n16) * PLANE_OUT
                       + (y0 + wave * 2 + mt) * WO + x0 + quad * 4;
            *(ffrag*)dst = acc[mt][nt];
        }
}

extern "C" void kernel_launch(void* const* d_in, const int* in_sizes, int n_in,
                              void* d_out, int out_size, void* d_ws, size_t ws_size,
                              hipStream_t stream) {
    const float* x  = (const float*)d_in[0];
    const float* w1 = (const float*)d_in[1];
    const float* b1 = (const float*)d_in[2];
    const float* w2 = (const float*)d_in[3];
    const float* b2 = (const float*)d_in[4];
    const float* wd = (const float*)d_in[5];
    float* y_out = (float*)d_out;
    float* off_out = y_out + (size_t)B_ * COUT * PLANE_OUT;   // (y, off) concat
    float* wsf = (float*)d_ws;
    u16* xt = (u16*)((char*)d_ws + XT_BYTE);
    const bool use_xt = ws_size >= XT_BYTE + XT_SIZE;

    prep_weights<<<324, 256, 0, stream>>>(w1, wd, w2, wsf);
    if (use_xt) {
        x_to_nhwc<<<(B_ * PLANE_IN + 255) / 256, 256, 0, stream>>>(x, xt);
        conv12<true><<<dim3(8, 8, B_), 256, 0, stream>>>(x, xt, b1, b2, wsf, off_out);
        deform_k<true><<<2048, 256, 0, stream>>>(x, xt, wsf, off_out, y_out);
    } else {
        conv12<false><<<dim3(8, 8, B_), 256, 0, stream>>>(x, xt, b1, b2, wsf, off_out);
        deform_k<false><<<2048, 256, 0, stream>>>(x, xt, wsf, off_out, y_out);
    }
}